// Round 16
// baseline (8623.735 us; speedup 1.0000x reference)
//
#include <hip/hip_runtime.h>
#include <hip/hip_bf16.h>

typedef __attribute__((ext_vector_type(4))) float f32x4;
typedef __attribute__((ext_vector_type(8))) __bf16 bf16x8;
typedef __attribute__((ext_vector_type(8))) unsigned short ushort8;

#define L_LAYERS 12
#define D_MODEL  1024
#define B_BATCH  16
#define T_TIME   2000
#define M_ROWS   (T_TIME * B_BATCH)   // 32000
#define H_HEADS  16
#define DH       64
#define SEGL     20
#define NSEG     (T_TIME / SEGL)      // 100
#define HGN      4                    // heads per attention block
#define QKVW     (3 * D_MODEL)        // packed q|k|v row width

// ---------- helpers ----------
__device__ __forceinline__ void gload_lds16(const void* g, void* l) {
  __builtin_amdgcn_global_load_lds((const __attribute__((address_space(1))) void*)g,
                                   (__attribute__((address_space(3))) void*)l, 16, 0, 0);
}
__device__ __forceinline__ float bf2f(unsigned short u) {
  union { unsigned int i; float f; } x; x.i = ((unsigned)u) << 16; return x.f;
}
__device__ __forceinline__ unsigned short f2bf(float f) {
  union { __hip_bfloat16 h; unsigned short u; } x; x.h = __float2bfloat16(f); return x.u;
}
__device__ __forceinline__ void unpack4(uint2 u, float* v) {
  v[0] = bf2f((unsigned short)(u.x & 0xffff));
  v[1] = bf2f((unsigned short)(u.x >> 16));
  v[2] = bf2f((unsigned short)(u.y & 0xffff));
  v[3] = bf2f((unsigned short)(u.y >> 16));
}
__device__ __forceinline__ uint2 pack4(const float* v) {
  uint2 u;
  u.x = (unsigned)f2bf(v[0]) | ((unsigned)f2bf(v[1]) << 16);
  u.y = (unsigned)f2bf(v[2]) | ((unsigned)f2bf(v[3]) << 16);
  return u;
}

// ---------- fused: x (B,T,D) fp32 -> h (T*B, D) bf16 AND hn = LN(h) bf16 ----------
__global__ __launch_bounds__(256)
void xpose_ln(const float* __restrict__ x, __hip_bfloat16* __restrict__ h,
              __hip_bfloat16* __restrict__ hn,
              const float* __restrict__ gamma, const float* __restrict__ beta) {
  const int r = blockIdx.x, t = threadIdx.x;   // r = tt*16 + b
  const int tt = r >> 4, b = r & 15;
  const float4 v = reinterpret_cast<const float4*>(x + ((size_t)b * T_TIME + tt) * D_MODEL)[t];
  float vv[4] = {v.x, v.y, v.z, v.w};
  *reinterpret_cast<uint2*>(h + (size_t)r * D_MODEL + t * 4) = pack4(vv);
  float s  = v.x + v.y + v.z + v.w;
  float sq = v.x * v.x + v.y * v.y + v.z * v.z + v.w * v.w;
#pragma unroll
  for (int off = 32; off >= 1; off >>= 1) { s += __shfl_xor(s, off); sq += __shfl_xor(sq, off); }
  __shared__ float ss[4], ssq[4];
  if ((t & 63) == 0) { ss[t >> 6] = s; ssq[t >> 6] = sq; }
  __syncthreads();
  s = ss[0] + ss[1] + ss[2] + ss[3];
  sq = ssq[0] + ssq[1] + ssq[2] + ssq[3];
  const float mu = s * (1.0f / D_MODEL);
  const float rstd = rsqrtf(sq * (1.0f / D_MODEL) - mu * mu + 1e-5f);
  const float4 g = reinterpret_cast<const float4*>(gamma)[t];
  const float4 bb = reinterpret_cast<const float4*>(beta)[t];
  float o[4] = {(v.x - mu) * rstd * g.x + bb.x, (v.y - mu) * rstd * g.y + bb.y,
                (v.z - mu) * rstd * g.z + bb.z, (v.w - mu) * rstd * g.w + bb.w};
  *reinterpret_cast<uint2*>(hn + (size_t)r * D_MODEL + t * 4) = pack4(o);
}

// ---------- weight transpose fp32 W[Kd][Nd] -> bf16 Wt[Nd][Kd], z-batched w/ out stride ----------
__global__ __launch_bounds__(256)
void trans_w(const float* __restrict__ W, __hip_bfloat16* __restrict__ Wt, int Kd, int Nd,
             size_t ostride) {
  __shared__ float tbuf[32][33];
  const size_t ibase = (size_t)blockIdx.z * Kd * Nd;
  const size_t obase = (size_t)blockIdx.z * ostride;
  const int n0 = blockIdx.x * 32, k0 = blockIdx.y * 32;
  const int tx = threadIdx.x & 31, ty = threadIdx.x >> 5;
#pragma unroll
  for (int i = 0; i < 4; i++)
    tbuf[ty + i * 8][tx] = W[ibase + (size_t)(k0 + ty + i * 8) * Nd + n0 + tx];
  __syncthreads();
#pragma unroll
  for (int i = 0; i < 4; i++)
    Wt[obase + (size_t)(n0 + ty + i * 8) * Kd + k0 + tx] = __float2bfloat16(tbuf[tx][ty + i * 8]);
}

// ---------- LayerNorm: bf16 in -> bf16 out (in-place safe) ----------
__global__ __launch_bounds__(256)
void ln_k(const __hip_bfloat16* __restrict__ in, __hip_bfloat16* __restrict__ out,
          const float* __restrict__ gamma, const float* __restrict__ beta) {
  const int r = blockIdx.x, t = threadIdx.x;
  float v[4];
  unpack4(*reinterpret_cast<const uint2*>(in + (size_t)r * D_MODEL + t * 4), v);
  float s  = v[0] + v[1] + v[2] + v[3];
  float sq = v[0] * v[0] + v[1] * v[1] + v[2] * v[2] + v[3] * v[3];
#pragma unroll
  for (int off = 32; off >= 1; off >>= 1) { s += __shfl_xor(s, off); sq += __shfl_xor(sq, off); }
  __shared__ float ss[4], ssq[4];
  if ((t & 63) == 0) { ss[t >> 6] = s; ssq[t >> 6] = sq; }
  __syncthreads();
  s = ss[0] + ss[1] + ss[2] + ss[3];
  sq = ssq[0] + ssq[1] + ssq[2] + ssq[3];
  const float mu = s * (1.0f / D_MODEL);
  const float rstd = rsqrtf(sq * (1.0f / D_MODEL) - mu * mu + 1e-5f);
  const float4 g = reinterpret_cast<const float4*>(gamma)[t];
  const float4 bb = reinterpret_cast<const float4*>(beta)[t];
  float o[4] = {(v[0] - mu) * rstd * g.x + bb.x, (v[1] - mu) * rstd * g.y + bb.y,
                (v[2] - mu) * rstd * g.z + bb.z, (v[3] - mu) * rstd * g.w + bb.w};
  *reinterpret_cast<uint2*>(out + (size_t)r * D_MODEL + t * 4) = pack4(o);
}

// ---------- fused dual LN: y = LN_a(in) -> hout bf16;  LN_b(y) -> hn bf16 (in-place safe) ----------
__global__ __launch_bounds__(256)
void dual_ln(const __hip_bfloat16* __restrict__ in, __hip_bfloat16* __restrict__ hout,
             __hip_bfloat16* __restrict__ hn,
             const float* __restrict__ ga, const float* __restrict__ ba,
             const float* __restrict__ gb, const float* __restrict__ bb_) {
  const int r = blockIdx.x, t = threadIdx.x;
  float v[4];
  unpack4(*reinterpret_cast<const uint2*>(in + (size_t)r * D_MODEL + t * 4), v);
  float s  = v[0] + v[1] + v[2] + v[3];
  float sq = v[0] * v[0] + v[1] * v[1] + v[2] * v[2] + v[3] * v[3];
#pragma unroll
  for (int off = 32; off >= 1; off >>= 1) { s += __shfl_xor(s, off); sq += __shfl_xor(sq, off); }
  __shared__ float ss[4], ssq[4], ss2[4], ssq2[4];
  if ((t & 63) == 0) { ss[t >> 6] = s; ssq[t >> 6] = sq; }
  __syncthreads();
  s = ss[0] + ss[1] + ss[2] + ss[3];
  sq = ssq[0] + ssq[1] + ssq[2] + ssq[3];
  const float mu1 = s * (1.0f / D_MODEL);
  const float rstd1 = rsqrtf(sq * (1.0f / D_MODEL) - mu1 * mu1 + 1e-5f);
  const float4 g1 = reinterpret_cast<const float4*>(ga)[t];
  const float4 b1 = reinterpret_cast<const float4*>(ba)[t];
  float y[4] = {(v[0] - mu1) * rstd1 * g1.x + b1.x, (v[1] - mu1) * rstd1 * g1.y + b1.y,
                (v[2] - mu1) * rstd1 * g1.z + b1.z, (v[3] - mu1) * rstd1 * g1.w + b1.w};
  *reinterpret_cast<uint2*>(hout + (size_t)r * D_MODEL + t * 4) = pack4(y);
  float s2  = y[0] + y[1] + y[2] + y[3];
  float sq2 = y[0] * y[0] + y[1] * y[1] + y[2] * y[2] + y[3] * y[3];
#pragma unroll
  for (int off = 32; off >= 1; off >>= 1) { s2 += __shfl_xor(s2, off); sq2 += __shfl_xor(sq2, off); }
  if ((t & 63) == 0) { ss2[t >> 6] = s2; ssq2[t >> 6] = sq2; }
  __syncthreads();
  s2 = ss2[0] + ss2[1] + ss2[2] + ss2[3];
  sq2 = ssq2[0] + ssq2[1] + ssq2[2] + ssq2[3];
  const float mu2 = s2 * (1.0f / D_MODEL);
  const float rstd2 = rsqrtf(sq2 * (1.0f / D_MODEL) - mu2 * mu2 + 1e-5f);
  const float4 g2 = reinterpret_cast<const float4*>(gb)[t];
  const float4 b2 = reinterpret_cast<const float4*>(bb_)[t];
  float o[4] = {(y[0] - mu2) * rstd2 * g2.x + b2.x, (y[1] - mu2) * rstd2 * g2.y + b2.y,
                (y[2] - mu2) * rstd2 * g2.z + b2.z, (y[3] - mu2) * rstd2 * g2.w + b2.w};
  *reinterpret_cast<uint2*>(hn + (size_t)r * D_MODEL + t * 4) = pack4(o);
}

// ---------- GEMM v6: 128x128 tile, BK=64, 4 waves, 64KB dbuf LDS -> 2 blocks/CU ----------
// Round-16 change: tile 256->128 (m92/m103 evidence: 2-barrier 128²=912 TF > 256²=792)
// to regain inter-block overlap (m114) covering the barrier drains. Same XOR swizzle,
// counted vmcnt(8), bijective XCD swizzle, coalesced LDS epilogue as before.
enum { EPI_BF16 = 0, EPI_RELU = 1, EPI_RES = 2 };

template <int EPI>
__global__ __launch_bounds__(256, 2)
void gemm_bt(const __hip_bfloat16* __restrict__ A, const __hip_bfloat16* __restrict__ Bt,
             const float* __restrict__ bias0, const float* __restrict__ bias1, int bsel,
             const __hip_bfloat16* __restrict__ resid, __hip_bfloat16* __restrict__ Cv,
             int N, int K, int lda, int ldc) {
  __shared__ __hip_bfloat16 smem[2][2][128][64];   // [A|B][dbuf][row][k] = 64 KB
  const int tid = threadIdx.x;
  const int wv = tid >> 6, ln = tid & 63;
  const int NT = N >> 7;
  const int nwg = gridDim.x;
  const int q8 = nwg >> 3, r8 = nwg & 7;
  const int xcd = blockIdx.x & 7, lid = blockIdx.x >> 3;
  const int swz = (xcd < r8 ? xcd * (q8 + 1) : r8 * (q8 + 1) + (xcd - r8) * q8) + lid;
  const int mt = swz / NT, nt = swz % NT;

  const __hip_bfloat16* ag = A  + (size_t)mt * 128 * lda;
  const __hip_bfloat16* bg = Bt + (size_t)nt * 128 * K;
  const int sr = tid >> 3, scc = tid & 7;   // staging row base (0..31), chunk slot (0..7)

  auto stage = [&](int buf, int k0) {       // 4+4 gload_lds per thread
#pragma unroll
    for (int it = 0; it < 4; it++) {
      const int r = it * 32 + sr;
      const int cs = scc ^ (r & 7);         // inverse swizzle on SOURCE
      gload_lds16(ag + (size_t)r * lda + k0 + cs * 8,
                  (char*)&smem[0][buf][0][0] + (it * 256 + tid) * 16);
    }
#pragma unroll
    for (int it = 0; it < 4; it++) {
      const int r = it * 32 + sr;
      const int cs = scc ^ (r & 7);
      gload_lds16(bg + (size_t)r * K + k0 + cs * 8,
                  (char*)&smem[1][buf][0][0] + (it * 256 + tid) * 16);
    }
  };

  const int wr = wv >> 1, wc = wv & 1;      // 2 x 2 wave grid, per-wave 64x64
  const int lr = ln & 15, lk = ln >> 4;
  const int l7 = lr & 7;
  f32x4 acc[4][4] = {};

  stage(0, 0);
  int cur = 0;
  const int ntiles = K >> 6;
  for (int t = 0; t < ntiles; ++t) {
    const int k0 = t << 6;
    if (t + 1 < ntiles) {
      stage(cur ^ 1, k0 + 64);
      asm volatile("s_waitcnt vmcnt(8)" ::: "memory");   // tile t's 8 loads landed
    } else {
      asm volatile("s_waitcnt vmcnt(0)" ::: "memory");
    }
    __builtin_amdgcn_s_barrier();
    __builtin_amdgcn_sched_barrier(0);
    const char* ab = (const char*)&smem[0][cur][0][0];
    const char* bb = (const char*)&smem[1][cur][0][0];
#pragma unroll
    for (int kb = 0; kb < 2; kb++) {
      const int slot = (kb * 4 + lk) ^ l7;
      bf16x8 af[4], bfr[4];
#pragma unroll
      for (int n = 0; n < 4; n++)
        bfr[n] = *reinterpret_cast<const bf16x8*>(bb + ((wc * 64 + n * 16 + lr) * 8 + slot) * 16);
#pragma unroll
      for (int m = 0; m < 4; m++)
        af[m] = *reinterpret_cast<const bf16x8*>(ab + ((wr * 64 + m * 16 + lr) * 8 + slot) * 16);
#pragma unroll
      for (int m = 0; m < 4; m++)
#pragma unroll
        for (int n = 0; n < 4; n++)
          acc[m][n] = __builtin_amdgcn_mfma_f32_16x16x32_bf16(af[m], bfr[n], acc[m][n], 0, 0, 0);
    }
    __builtin_amdgcn_sched_barrier(0);
    __builtin_amdgcn_s_barrier();
    cur ^= 1;
  }
  // ---- coalesced epilogue: per-wave private 8 KB LDS tile [64 rows][128 B] ----
  char* tile = (char*)&smem[0][0][0][0] + wv * 8192;
#pragma unroll
  for (int n = 0; n < 4; n++) {
    const int colw = n * 16 + lr;                 // col within wave's 64
    const int col = nt * 128 + wc * 64 + colw;    // global col
    const float bv = (col < bsel) ? bias0[col] : bias1[col - bsel];
#pragma unroll
    for (int m = 0; m < 4; m++) {
#pragma unroll
      for (int j = 0; j < 4; j++) {
        const int lrow = m * 16 + lk * 4 + j;     // row within wave's 64
        float v = acc[m][n][j] + bv;
        if constexpr (EPI == EPI_RELU) v = fmaxf(v, 0.0f);
        const int phys = (((colw >> 3) ^ (lrow & 7)) << 4) + (colw & 7) * 2;
        *reinterpret_cast<unsigned short*>(tile + lrow * 128 + phys) = f2bf(v);
      }
    }
  }
  // read back own region (ds-dependency within wave; no barrier needed)
#pragma unroll
  for (int pass = 0; pass < 8; pass++) {
    const int lrow = pass * 8 + (ln >> 3);
    const int Lc = ln & 7;
    const uint4 val = *reinterpret_cast<const uint4*>(tile + lrow * 128 + ((Lc ^ (lrow & 7)) << 4));
    const size_t rg = (size_t)mt * 128 + wr * 64 + lrow;
    const int cg = nt * 128 + wc * 64 + Lc * 8;
    __hip_bfloat16* cp = Cv + rg * (size_t)ldc + cg;
    if constexpr (EPI == EPI_RES) {
      const uint4 rv = *reinterpret_cast<const uint4*>(resid + rg * (size_t)ldc + cg);
      const unsigned short* tv = reinterpret_cast<const unsigned short*>(&val);
      const unsigned short* rr = reinterpret_cast<const unsigned short*>(&rv);
      unsigned short pk[8];
#pragma unroll
      for (int e = 0; e < 8; e++) pk[e] = f2bf(bf2f(tv[e]) + bf2f(rr[e]));
      *reinterpret_cast<uint4*>(cp) = *reinterpret_cast<const uint4*>(pk);
    } else {
      *reinterpret_cast<uint4*>(cp) = val;
    }
  }
}

// ---------- block-diagonal attention on packed qkv [M][q|k|v] (ctx in-place over q slice) ----------
__global__ __launch_bounds__(256, 4)
void attn_k(__hip_bfloat16* __restrict__ qkv) {
  __shared__ __hip_bfloat16 kls[SEGL][HGN * DH];   // 10 KB: K slice; reused as ctx tile
  __shared__ __hip_bfloat16 vls[SEGL][HGN * DH];   // 10 KB: V slice
  __shared__ float sls[HGN][SEGL][SEGL];           // 6.4 KB: scores
  const int blk = blockIdx.x;
  const int hg = blk & 3;
  const int sb = blk >> 2;
  const int s = sb >> 4, b = sb & 15;
  const size_t row0 = (size_t)s * SEGL * B_BATCH + b;
  const int tid = threadIdx.x;
  const int colbase = hg * (HGN * DH);
#pragma unroll
  for (int it = 0; it < 3; it++) {
    const int c = it * 256 + tid;
    if (c < SEGL * 32) {
      const int j = c >> 5, off = (c & 31) * 8;
      gload_lds16(qkv + (row0 + (size_t)j * B_BATCH) * QKVW + D_MODEL + colbase + off,
                  (char*)kls + c * 16);
    }
  }
#pragma unroll
  for (int it = 0; it < 3; it++) {
    const int c = it * 256 + tid;
    if (c < SEGL * 32) {
      const int j = c >> 5, off = (c & 31) * 8;
      gload_lds16(qkv + (row0 + (size_t)j * B_BATCH) * QKVW + 2 * D_MODEL + colbase + off,
                  (char*)vls + c * 16);
    }
  }
  const bool active = tid < HGN * SEGL;
  const int hh = tid / SEGL;
  const int i  = tid % SEGL;
  ushort8 qv[8];
  if (active) {
    const __hip_bfloat16* qp = qkv + (row0 + (size_t)i * B_BATCH) * QKVW + (colbase + hh * DH);
#pragma unroll
    for (int c = 0; c < 8; c++) qv[c] = reinterpret_cast<const ushort8*>(qp)[c];
  }
  __syncthreads();
  float inv = 0.0f;
  if (active) {
#pragma unroll 1
    for (int j = 0; j < SEGL; j++) {
      float a0 = 0, a1 = 0;
#pragma unroll
      for (int c = 0; c < 8; c++) {
        ushort8 u = *reinterpret_cast<const ushort8*>(&kls[j][hh * DH + c * 8]);
#pragma unroll
        for (int e = 0; e < 8; e += 2) {
          a0 += bf2f(qv[c][e]) * bf2f(u[e]);
          a1 += bf2f(qv[c][e + 1]) * bf2f(u[e + 1]);
        }
      }
      sls[hh][i][j] = (a0 + a1) * 0.125f;
    }
    float mx = -1e30f;
#pragma unroll 1
    for (int j = 0; j < SEGL; j++) mx = fmaxf(mx, sls[hh][i][j]);
    float sum = 0.0f;
#pragma unroll 1
    for (int j = 0; j < SEGL; j++) { float e = __expf(sls[hh][i][j] - mx); sls[hh][i][j] = e; sum += e; }
    inv = 1.0f / sum;
  }
  __syncthreads();
  if (active) {
#pragma unroll
    for (int d0 = 0; d0 < DH; d0 += 8) {
      float acc[8] = {};
#pragma unroll 1
      for (int j = 0; j < SEGL; j++) {
        const float pj = sls[hh][i][j];
        ushort8 u = *reinterpret_cast<const ushort8*>(&vls[j][hh * DH + d0]);
#pragma unroll
        for (int e = 0; e < 8; e++) acc[e] += pj * bf2f(u[e]);
      }
      unsigned short pk[8];
#pragma unroll
      for (int e = 0; e < 8; e++) pk[e] = f2bf(acc[e] * inv);
      const int colr = hh * DH + ((d0 + i * 8) & (DH - 1));
      *reinterpret_cast<uint4*>(&kls[i][colr]) = *reinterpret_cast<uint4*>(pk);
    }
  }
  __syncthreads();
#pragma unroll
  for (int it = 0; it < 3; it++) {
    const int c = it * 256 + tid;
    if (c < SEGL * 32) {
      const int j = c >> 5, off = (c & 31) * 8;
      const int hl = off >> 6, d = off & (DH - 1);
      const int colr = hl * DH + ((d + j * 8) & (DH - 1));
      *reinterpret_cast<uint4*>(qkv + (row0 + (size_t)j * B_BATCH) * QKVW + colbase + off) =
          *reinterpret_cast<const uint4*>(&kls[j][colr]);
    }
  }
}

// ---------- final: pooled = mean_b h ; out = pooled @ fc_w + fc_b ----------
__global__ __launch_bounds__(256)
void pool_fc(const __hip_bfloat16* __restrict__ h, const float* __restrict__ fcw,
             const float* __restrict__ fcb, float* __restrict__ out) {
  const int t = blockIdx.x, tid = threadIdx.x;
  float a[4] = {0, 0, 0, 0};
#pragma unroll
  for (int b = 0; b < B_BATCH; b++) {
    float v[4];
    unpack4(*reinterpret_cast<const uint2*>(h + ((size_t)t * B_BATCH + b) * D_MODEL + tid * 4), v);
#pragma unroll
    for (int e = 0; e < 4; e++) a[e] += v[e];
  }
  const int d0 = tid * 4;
  float pacc[5];
#pragma unroll
  for (int c = 0; c < 5; c++)
    pacc[c] = (a[0] * fcw[(d0 + 0) * 5 + c] + a[1] * fcw[(d0 + 1) * 5 + c] +
               a[2] * fcw[(d0 + 2) * 5 + c] + a[3] * fcw[(d0 + 3) * 5 + c]) * (1.0f / B_BATCH);
#pragma unroll
  for (int off = 32; off >= 1; off >>= 1)
#pragma unroll
    for (int c = 0; c < 5; c++) pacc[c] += __shfl_xor(pacc[c], off);
  __shared__ float red[4][5];
  if ((tid & 63) == 0) {
#pragma unroll
    for (int c = 0; c < 5; c++) red[tid >> 6][c] = pacc[c];
  }
  __syncthreads();
  if (tid < 5)
    out[(size_t)t * 5 + tid] = red[0][tid] + red[1][tid] + red[2][tid] + red[3][tid] + fcb[tid];
}

// ---------- launch ----------
extern "C" void kernel_launch(void* const* d_in, const int* in_sizes, int n_in,
                              void* d_out, int out_size, void* d_ws, size_t ws_size,
                              hipStream_t stream) {
  const float* x    = (const float*)d_in[0];
  const float* lnp  = (const float*)d_in[2];
  const float* Wq   = (const float*)d_in[3];
  const float* bq   = (const float*)d_in[4];
  const float* Wkv  = (const float*)d_in[5];
  const float* bkv  = (const float*)d_in[6];
  const float* Wout = (const float*)d_in[7];
  const float* bout = (const float*)d_in[8];
  const float* W1   = (const float*)d_in[9];
  const float* b1   = (const float*)d_in[10];
  const float* W2   = (const float*)d_in[11];
  const float* b2   = (const float*)d_in[12];
  const float* fcw  = (const float*)d_in[13];
  const float* fcb  = (const float*)d_in[14];

  char* p = (char*)d_ws;
  size_t off = 0;
  auto take = [&](size_t bytes) -> char* { char* q = p + off; off += (bytes + 255) & ~(size_t)255; return q; };

  __hip_bfloat16* h    = (__hip_bfloat16*)take((size_t)M_ROWS * D_MODEL * 2);
  __hip_bfloat16* hn   = (__hip_bfloat16*)take((size_t)M_ROWS * D_MODEL * 2);
  __hip_bfloat16* qkvb = (__hip_bfloat16*)take((size_t)M_ROWS * QKVW * 2);
  __hip_bfloat16* f1   = qkvb + D_MODEL;   // strided [M][1024] at ldc=QKVW (k slice, dead post-attn)

  const size_t WL  = (size_t)D_MODEL * D_MODEL;
  const size_t WQKV = 3 * WL;
  const size_t fullBytes = (L_LAYERS * (WQKV + 3 * WL)) * 2;
  const bool full = ws_size >= off + fullBytes + (size_t)(16 << 20);

  __hip_bfloat16 *WqkvT, *WoutT, *W1T, *W2T;
  if (full) {
    WqkvT = (__hip_bfloat16*)take(L_LAYERS * WQKV * 2);
    WoutT = (__hip_bfloat16*)take(L_LAYERS * WL * 2);
    W1T   = (__hip_bfloat16*)take(L_LAYERS * WL * 2);
    W2T   = (__hip_bfloat16*)take(L_LAYERS * WL * 2);
    trans_w<<<dim3(32, 32, L_LAYERS), 256, 0, stream>>>(Wq,  WqkvT,      D_MODEL, D_MODEL,     WQKV);
    trans_w<<<dim3(64, 32, L_LAYERS), 256, 0, stream>>>(Wkv, WqkvT + WL, D_MODEL, 2 * D_MODEL, WQKV);
    trans_w<<<dim3(32, 32, L_LAYERS), 256, 0, stream>>>(Wout, WoutT, D_MODEL, D_MODEL, WL);
    trans_w<<<dim3(32, 32, L_LAYERS), 256, 0, stream>>>(W1,   W1T,   D_MODEL, D_MODEL, WL);
    trans_w<<<dim3(32, 32, L_LAYERS), 256, 0, stream>>>(W2,   W2T,   D_MODEL, D_MODEL, WL);
  } else {
    WqkvT = (__hip_bfloat16*)take(WQKV * 2);
    WoutT = (__hip_bfloat16*)take(WL * 2);
    W1T   = (__hip_bfloat16*)take(WL * 2);
    W2T   = (__hip_bfloat16*)take(WL * 2);
  }

  const float* g00 = lnp;
  const float* b00 = lnp + D_MODEL;
  xpose_ln<<<M_ROWS, 256, 0, stream>>>(x, h, hn, g00, b00);

  const int MT = M_ROWS / 128;   // 250
  const int BSEL_OFF = 1 << 30;
  for (int l = 0; l < L_LAYERS; l++) {
    const size_t lw = (size_t)l * WL;
    const __hip_bfloat16* wqkv = full ? WqkvT + l * WQKV : WqkvT;
    const __hip_bfloat16* wout = full ? WoutT + lw : WoutT;
    const __hip_bfloat16* w1   = full ? W1T   + lw : W1T;
    const __hip_bfloat16* w2   = full ? W2T   + lw : W2T;
    if (!full) {
      trans_w<<<dim3(32, 32, 1), 256, 0, stream>>>(Wq + lw,      WqkvT,      D_MODEL, D_MODEL,     0);
      trans_w<<<dim3(64, 32, 1), 256, 0, stream>>>(Wkv + 2 * lw, WqkvT + WL, D_MODEL, 2 * D_MODEL, 0);
      trans_w<<<dim3(32, 32, 1), 256, 0, stream>>>(Wout + lw, WoutT, D_MODEL, D_MODEL, 0);
      trans_w<<<dim3(32, 32, 1), 256, 0, stream>>>(W1 + lw,   W1T,   D_MODEL, D_MODEL, 0);
      trans_w<<<dim3(32, 32, 1), 256, 0, stream>>>(W2 + lw,   W2T,   D_MODEL, D_MODEL, 0);
    }
    const float* g2 = lnp + ((size_t)l * 6 + 2) * D_MODEL;
    const float* g3 = lnp + ((size_t)l * 6 + 3) * D_MODEL;
    const float* g4 = lnp + ((size_t)l * 6 + 4) * D_MODEL;
    const float* g5 = lnp + ((size_t)l * 6 + 5) * D_MODEL;

    // fused qkv projection: C = [q|k|v], N=3072 (grid 250 x 24)
    gemm_bt<EPI_BF16><<<dim3(MT * 24), 256, 0, stream>>>(
        hn, wqkv, bq + (size_t)l * D_MODEL, bkv + (size_t)l * 2 * D_MODEL, D_MODEL,
        nullptr, qkvb, QKVW, D_MODEL, D_MODEL, QKVW);
    attn_k<<<NSEG * B_BATCH * HGN, 256, 0, stream>>>(qkvb);
    gemm_bt<EPI_RES><<<dim3(MT * 8), 256, 0, stream>>>(
        qkvb, wout, bout + (size_t)l * D_MODEL, bout + (size_t)l * D_MODEL, BSEL_OFF,
        h, h, D_MODEL, D_MODEL, QKVW, D_MODEL);
    ln_k<<<M_ROWS, 256, 0, stream>>>(h, hn, g2, g3);
    gemm_bt<EPI_RELU><<<dim3(MT * 8), 256, 0, stream>>>(
        hn, w1, b1 + (size_t)l * D_MODEL, b1 + (size_t)l * D_MODEL, BSEL_OFF,
        nullptr, f1, D_MODEL, D_MODEL, D_MODEL, QKVW);
    gemm_bt<EPI_RES><<<dim3(MT * 8), 256, 0, stream>>>(
        f1, w2, b2 + (size_t)l * D_MODEL, b2 + (size_t)l * D_MODEL, BSEL_OFF,
        h, h, D_MODEL, D_MODEL, QKVW, D_MODEL);
    if (l + 1 < L_LAYERS) {
      const float* g0n = lnp + ((size_t)(l + 1) * 6 + 0) * D_MODEL;
      const float* b0n = lnp + ((size_t)(l + 1) * 6 + 1) * D_MODEL;
      dual_ln<<<M_ROWS, 256, 0, stream>>>(h, h, hn, g4, g5, g0n, b0n);
    } else {
      ln_k<<<M_ROWS, 256, 0, stream>>>(h, h, g4, g5);
    }
  }

  pool_fc<<<T_TIME, 256, 0, stream>>>(h, fcw, fcb, (float*)d_out);
}

// Round 17
// 8185.390 us; speedup vs baseline: 1.0536x; 1.0536x over previous
//
#include <hip/hip_runtime.h>
#include <hip/hip_bf16.h>

typedef __attribute__((ext_vector_type(4))) float f32x4;
typedef __attribute__((ext_vector_type(8))) __bf16 bf16x8;
typedef __attribute__((ext_vector_type(8))) unsigned short ushort8;

#define L_LAYERS 12
#define D_MODEL  1024
#define B_BATCH  16
#define T_TIME   2000
#define M_ROWS   (T_TIME * B_BATCH)   // 32000
#define H_HEADS  16
#define DH       64
#define SEGL     20
#define NSEG     (T_TIME / SEGL)      // 100
#define HGN      4                    // heads per attention block
#define QKVW     (3 * D_MODEL)        // packed q|k|v row width

// ---------- helpers ----------
__device__ __forceinline__ void gload_lds16(const void* g, void* l) {
  __builtin_amdgcn_global_load_lds((const __attribute__((address_space(1))) void*)g,
                                   (__attribute__((address_space(3))) void*)l, 16, 0, 0);
}
__device__ __forceinline__ float bf2f(unsigned short u) {
  union { unsigned int i; float f; } x; x.i = ((unsigned)u) << 16; return x.f;
}
__device__ __forceinline__ unsigned short f2bf(float f) {
  union { __hip_bfloat16 h; unsigned short u; } x; x.h = __float2bfloat16(f); return x.u;
}
__device__ __forceinline__ void unpack4(uint2 u, float* v) {
  v[0] = bf2f((unsigned short)(u.x & 0xffff));
  v[1] = bf2f((unsigned short)(u.x >> 16));
  v[2] = bf2f((unsigned short)(u.y & 0xffff));
  v[3] = bf2f((unsigned short)(u.y >> 16));
}
__device__ __forceinline__ uint2 pack4(const float* v) {
  uint2 u;
  u.x = (unsigned)f2bf(v[0]) | ((unsigned)f2bf(v[1]) << 16);
  u.y = (unsigned)f2bf(v[2]) | ((unsigned)f2bf(v[3]) << 16);
  return u;
}

// ---------- fused: x (B,T,D) fp32 -> h (T*B, D) bf16 AND hn = LN(h) bf16 ----------
__global__ __launch_bounds__(256)
void xpose_ln(const float* __restrict__ x, __hip_bfloat16* __restrict__ h,
              __hip_bfloat16* __restrict__ hn,
              const float* __restrict__ gamma, const float* __restrict__ beta) {
  const int r = blockIdx.x, t = threadIdx.x;   // r = tt*16 + b
  const int tt = r >> 4, b = r & 15;
  const float4 v = reinterpret_cast<const float4*>(x + ((size_t)b * T_TIME + tt) * D_MODEL)[t];
  float vv[4] = {v.x, v.y, v.z, v.w};
  *reinterpret_cast<uint2*>(h + (size_t)r * D_MODEL + t * 4) = pack4(vv);
  float s  = v.x + v.y + v.z + v.w;
  float sq = v.x * v.x + v.y * v.y + v.z * v.z + v.w * v.w;
#pragma unroll
  for (int off = 32; off >= 1; off >>= 1) { s += __shfl_xor(s, off); sq += __shfl_xor(sq, off); }
  __shared__ float ss[4], ssq[4];
  if ((t & 63) == 0) { ss[t >> 6] = s; ssq[t >> 6] = sq; }
  __syncthreads();
  s = ss[0] + ss[1] + ss[2] + ss[3];
  sq = ssq[0] + ssq[1] + ssq[2] + ssq[3];
  const float mu = s * (1.0f / D_MODEL);
  const float rstd = rsqrtf(sq * (1.0f / D_MODEL) - mu * mu + 1e-5f);
  const float4 g = reinterpret_cast<const float4*>(gamma)[t];
  const float4 bb = reinterpret_cast<const float4*>(beta)[t];
  float o[4] = {(v.x - mu) * rstd * g.x + bb.x, (v.y - mu) * rstd * g.y + bb.y,
                (v.z - mu) * rstd * g.z + bb.z, (v.w - mu) * rstd * g.w + bb.w};
  *reinterpret_cast<uint2*>(hn + (size_t)r * D_MODEL + t * 4) = pack4(o);
}

// ---------- weight transpose fp32 W[Kd][Nd] -> bf16 Wt[Nd][Kd], z-batched w/ out stride ----------
__global__ __launch_bounds__(256)
void trans_w(const float* __restrict__ W, __hip_bfloat16* __restrict__ Wt, int Kd, int Nd,
             size_t ostride) {
  __shared__ float tbuf[32][33];
  const size_t ibase = (size_t)blockIdx.z * Kd * Nd;
  const size_t obase = (size_t)blockIdx.z * ostride;
  const int n0 = blockIdx.x * 32, k0 = blockIdx.y * 32;
  const int tx = threadIdx.x & 31, ty = threadIdx.x >> 5;
#pragma unroll
  for (int i = 0; i < 4; i++)
    tbuf[ty + i * 8][tx] = W[ibase + (size_t)(k0 + ty + i * 8) * Nd + n0 + tx];
  __syncthreads();
#pragma unroll
  for (int i = 0; i < 4; i++)
    Wt[obase + (size_t)(n0 + ty + i * 8) * Kd + k0 + tx] = __float2bfloat16(tbuf[tx][ty + i * 8]);
}

// ---------- LayerNorm: bf16 in -> bf16 out (in-place safe) ----------
__global__ __launch_bounds__(256)
void ln_k(const __hip_bfloat16* __restrict__ in, __hip_bfloat16* __restrict__ out,
          const float* __restrict__ gamma, const float* __restrict__ beta) {
  const int r = blockIdx.x, t = threadIdx.x;
  float v[4];
  unpack4(*reinterpret_cast<const uint2*>(in + (size_t)r * D_MODEL + t * 4), v);
  float s  = v[0] + v[1] + v[2] + v[3];
  float sq = v[0] * v[0] + v[1] * v[1] + v[2] * v[2] + v[3] * v[3];
#pragma unroll
  for (int off = 32; off >= 1; off >>= 1) { s += __shfl_xor(s, off); sq += __shfl_xor(sq, off); }
  __shared__ float ss[4], ssq[4];
  if ((t & 63) == 0) { ss[t >> 6] = s; ssq[t >> 6] = sq; }
  __syncthreads();
  s = ss[0] + ss[1] + ss[2] + ss[3];
  sq = ssq[0] + ssq[1] + ssq[2] + ssq[3];
  const float mu = s * (1.0f / D_MODEL);
  const float rstd = rsqrtf(sq * (1.0f / D_MODEL) - mu * mu + 1e-5f);
  const float4 g = reinterpret_cast<const float4*>(gamma)[t];
  const float4 bb = reinterpret_cast<const float4*>(beta)[t];
  float o[4] = {(v[0] - mu) * rstd * g.x + bb.x, (v[1] - mu) * rstd * g.y + bb.y,
                (v[2] - mu) * rstd * g.z + bb.z, (v[3] - mu) * rstd * g.w + bb.w};
  *reinterpret_cast<uint2*>(out + (size_t)r * D_MODEL + t * 4) = pack4(o);
}

// ---------- fused dual LN: y = LN_a(in) -> hout bf16;  LN_b(y) -> hn bf16 (in-place safe) ----------
__global__ __launch_bounds__(256)
void dual_ln(const __hip_bfloat16* __restrict__ in, __hip_bfloat16* __restrict__ hout,
             __hip_bfloat16* __restrict__ hn,
             const float* __restrict__ ga, const float* __restrict__ ba,
             const float* __restrict__ gb, const float* __restrict__ bb_) {
  const int r = blockIdx.x, t = threadIdx.x;
  float v[4];
  unpack4(*reinterpret_cast<const uint2*>(in + (size_t)r * D_MODEL + t * 4), v);
  float s  = v[0] + v[1] + v[2] + v[3];
  float sq = v[0] * v[0] + v[1] * v[1] + v[2] * v[2] + v[3] * v[3];
#pragma unroll
  for (int off = 32; off >= 1; off >>= 1) { s += __shfl_xor(s, off); sq += __shfl_xor(sq, off); }
  __shared__ float ss[4], ssq[4], ss2[4], ssq2[4];
  if ((t & 63) == 0) { ss[t >> 6] = s; ssq[t >> 6] = sq; }
  __syncthreads();
  s = ss[0] + ss[1] + ss[2] + ss[3];
  sq = ssq[0] + ssq[1] + ssq[2] + ssq[3];
  const float mu1 = s * (1.0f / D_MODEL);
  const float rstd1 = rsqrtf(sq * (1.0f / D_MODEL) - mu1 * mu1 + 1e-5f);
  const float4 g1 = reinterpret_cast<const float4*>(ga)[t];
  const float4 b1 = reinterpret_cast<const float4*>(ba)[t];
  float y[4] = {(v[0] - mu1) * rstd1 * g1.x + b1.x, (v[1] - mu1) * rstd1 * g1.y + b1.y,
                (v[2] - mu1) * rstd1 * g1.z + b1.z, (v[3] - mu1) * rstd1 * g1.w + b1.w};
  *reinterpret_cast<uint2*>(hout + (size_t)r * D_MODEL + t * 4) = pack4(y);
  float s2  = y[0] + y[1] + y[2] + y[3];
  float sq2 = y[0] * y[0] + y[1] * y[1] + y[2] * y[2] + y[3] * y[3];
#pragma unroll
  for (int off = 32; off >= 1; off >>= 1) { s2 += __shfl_xor(s2, off); sq2 += __shfl_xor(sq2, off); }
  if ((t & 63) == 0) { ss2[t >> 6] = s2; ssq2[t >> 6] = sq2; }
  __syncthreads();
  s2 = ss2[0] + ss2[1] + ss2[2] + ss2[3];
  sq2 = ssq2[0] + ssq2[1] + ssq2[2] + ssq2[3];
  const float mu2 = s2 * (1.0f / D_MODEL);
  const float rstd2 = rsqrtf(sq2 * (1.0f / D_MODEL) - mu2 * mu2 + 1e-5f);
  const float4 g2 = reinterpret_cast<const float4*>(gb)[t];
  const float4 b2 = reinterpret_cast<const float4*>(bb_)[t];
  float o[4] = {(y[0] - mu2) * rstd2 * g2.x + b2.x, (y[1] - mu2) * rstd2 * g2.y + b2.y,
                (y[2] - mu2) * rstd2 * g2.z + b2.z, (y[3] - mu2) * rstd2 * g2.w + b2.w};
  *reinterpret_cast<uint2*>(hn + (size_t)r * D_MODEL + t * 4) = pack4(o);
}

// ---------- GEMM (round-15 best config: 256x256, BK=64, counted vmcnt, coalesced epilogue) ----------
enum { EPI_BF16 = 0, EPI_RELU = 1, EPI_RES = 2 };

template <int EPI>
__global__ __launch_bounds__(512, 2)
void gemm_bt(const __hip_bfloat16* __restrict__ A, const __hip_bfloat16* __restrict__ Bt,
             const float* __restrict__ bias0, const float* __restrict__ bias1, int bsel,
             const __hip_bfloat16* __restrict__ resid, __hip_bfloat16* __restrict__ Cv,
             int N, int K, int lda, int ldc) {
  __shared__ __hip_bfloat16 smem[2][2][256][64];   // [A|B][dbuf][row][k] = 128 KB
  const int tid = threadIdx.x;
  const int wv = tid >> 6, ln = tid & 63;
  const int NT = N >> 8;
  const int nwg = gridDim.x;
  const int q8 = nwg >> 3, r8 = nwg & 7;
  const int xcd = blockIdx.x & 7, lid = blockIdx.x >> 3;
  const int swz = (xcd < r8 ? xcd * (q8 + 1) : r8 * (q8 + 1) + (xcd - r8) * q8) + lid;
  const int mt = swz / NT, nt = swz % NT;

  const __hip_bfloat16* ag = A  + (size_t)mt * 256 * lda;
  const __hip_bfloat16* bg = Bt + (size_t)nt * 256 * K;
  const int sr = tid >> 3, scc = tid & 7;

  auto stage = [&](int buf, int k0) {
#pragma unroll
    for (int it = 0; it < 4; it++) {
      const int r = it * 64 + sr;
      const int cs = scc ^ (sr & 7);
      gload_lds16(ag + (size_t)r * lda + k0 + cs * 8,
                  (char*)&smem[0][buf][0][0] + (it * 512 + tid) * 16);
    }
#pragma unroll
    for (int it = 0; it < 4; it++) {
      const int r = it * 64 + sr;
      const int cs = scc ^ (sr & 7);
      gload_lds16(bg + (size_t)r * K + k0 + cs * 8,
                  (char*)&smem[1][buf][0][0] + (it * 512 + tid) * 16);
    }
  };

  const int wr = wv >> 2, wc = wv & 3;
  const int lr = ln & 15, lk = ln >> 4;
  const int l7 = lr & 7;
  f32x4 acc[8][4] = {};

  stage(0, 0);
  int cur = 0;
  const int ntiles = K >> 6;
  for (int t = 0; t < ntiles; ++t) {
    const int k0 = t << 6;
    if (t + 1 < ntiles) {
      stage(cur ^ 1, k0 + 64);
      asm volatile("s_waitcnt vmcnt(8)" ::: "memory");
    } else {
      asm volatile("s_waitcnt vmcnt(0)" ::: "memory");
    }
    __builtin_amdgcn_s_barrier();
    __builtin_amdgcn_sched_barrier(0);
    const char* ab = (const char*)&smem[0][cur][0][0];
    const char* bb = (const char*)&smem[1][cur][0][0];
#pragma unroll
    for (int kb = 0; kb < 2; kb++) {
      const int slot = (kb * 4 + lk) ^ l7;
      bf16x8 bfr[4];
#pragma unroll
      for (int n = 0; n < 4; n++)
        bfr[n] = *reinterpret_cast<const bf16x8*>(bb + ((wc * 64 + n * 16 + lr) * 8 + slot) * 16);
#pragma unroll
      for (int mq = 0; mq < 2; mq++) {
        bf16x8 af[4];
#pragma unroll
        for (int m = 0; m < 4; m++)
          af[m] = *reinterpret_cast<const bf16x8*>(ab + ((wr * 128 + (mq * 4 + m) * 16 + lr) * 8 + slot) * 16);
#pragma unroll
        for (int m = 0; m < 4; m++)
#pragma unroll
          for (int n = 0; n < 4; n++)
            acc[mq * 4 + m][n] = __builtin_amdgcn_mfma_f32_16x16x32_bf16(af[m], bfr[n], acc[mq * 4 + m][n], 0, 0, 0);
      }
    }
    __builtin_amdgcn_sched_barrier(0);
    __builtin_amdgcn_s_barrier();
    cur ^= 1;
  }
  // ---- coalesced epilogue: per-wave private 16 KB LDS tile [128 rows][128 B] ----
  char* tile = (char*)&smem[0][0][0][0] + wv * 16384;
#pragma unroll
  for (int n = 0; n < 4; n++) {
    const int colw = n * 16 + lr;                 // col within wave's 64
    const int col = nt * 256 + wc * 64 + colw;    // global col
    const float bv = (col < bsel) ? bias0[col] : bias1[col - bsel];
#pragma unroll
    for (int m = 0; m < 8; m++) {
#pragma unroll
      for (int j = 0; j < 4; j++) {
        const int lrow = m * 16 + lk * 4 + j;     // row within wave's 128
        float v = acc[m][n][j] + bv;
        if constexpr (EPI == EPI_RELU) v = fmaxf(v, 0.0f);
        const int phys = (((colw >> 3) ^ (lrow & 7)) << 4) + (colw & 7) * 2;
        *reinterpret_cast<unsigned short*>(tile + lrow * 128 + phys) = f2bf(v);
      }
    }
  }
  // read back own region (ds-dependency within wave; no barrier needed)
#pragma unroll
  for (int pass = 0; pass < 16; pass++) {
    const int lrow = pass * 8 + (ln >> 3);
    const int Lc = ln & 7;
    const uint4 val = *reinterpret_cast<const uint4*>(tile + lrow * 128 + ((Lc ^ (lrow & 7)) << 4));
    const size_t rg = (size_t)mt * 256 + wr * 128 + lrow;
    const int cg = nt * 256 + wc * 64 + Lc * 8;
    __hip_bfloat16* cp = Cv + rg * (size_t)ldc + cg;
    if constexpr (EPI == EPI_RES) {
      const uint4 rv = *reinterpret_cast<const uint4*>(resid + rg * (size_t)ldc + cg);
      const unsigned short* tv = reinterpret_cast<const unsigned short*>(&val);
      const unsigned short* rr = reinterpret_cast<const unsigned short*>(&rv);
      unsigned short pk[8];
#pragma unroll
      for (int e = 0; e < 8; e++) pk[e] = f2bf(bf2f(tv[e]) + bf2f(rr[e]));
      *reinterpret_cast<uint4*>(cp) = *reinterpret_cast<const uint4*>(pk);
    } else {
      *reinterpret_cast<uint4*>(cp) = val;
    }
  }
}

// ---------- block-diagonal attention on packed qkv [M][q|k|v] (ctx in-place over q slice) ----------
__global__ __launch_bounds__(256, 4)
void attn_k(__hip_bfloat16* __restrict__ qkv) {
  __shared__ __hip_bfloat16 kls[SEGL][HGN * DH];   // 10 KB: K slice; reused as ctx tile
  __shared__ __hip_bfloat16 vls[SEGL][HGN * DH];   // 10 KB: V slice
  __shared__ float sls[HGN][SEGL][SEGL];           // 6.4 KB: scores
  const int blk = blockIdx.x;
  const int hg = blk & 3;
  const int sb = blk >> 2;
  const int s = sb >> 4, b = sb & 15;
  const size_t row0 = (size_t)s * SEGL * B_BATCH + b;
  const int tid = threadIdx.x;
  const int colbase = hg * (HGN * DH);
#pragma unroll
  for (int it = 0; it < 3; it++) {
    const int c = it * 256 + tid;
    if (c < SEGL * 32) {
      const int j = c >> 5, off = (c & 31) * 8;
      gload_lds16(qkv + (row0 + (size_t)j * B_BATCH) * QKVW + D_MODEL + colbase + off,
                  (char*)kls + c * 16);
    }
  }
#pragma unroll
  for (int it = 0; it < 3; it++) {
    const int c = it * 256 + tid;
    if (c < SEGL * 32) {
      const int j = c >> 5, off = (c & 31) * 8;
      gload_lds16(qkv + (row0 + (size_t)j * B_BATCH) * QKVW + 2 * D_MODEL + colbase + off,
                  (char*)vls + c * 16);
    }
  }
  const bool active = tid < HGN * SEGL;
  const int hh = tid / SEGL;
  const int i  = tid % SEGL;
  ushort8 qv[8];
  if (active) {
    const __hip_bfloat16* qp = qkv + (row0 + (size_t)i * B_BATCH) * QKVW + (colbase + hh * DH);
#pragma unroll
    for (int c = 0; c < 8; c++) qv[c] = reinterpret_cast<const ushort8*>(qp)[c];
  }
  __syncthreads();
  float inv = 0.0f;
  if (active) {
#pragma unroll 1
    for (int j = 0; j < SEGL; j++) {
      float a0 = 0, a1 = 0;
#pragma unroll
      for (int c = 0; c < 8; c++) {
        ushort8 u = *reinterpret_cast<const ushort8*>(&kls[j][hh * DH + c * 8]);
#pragma unroll
        for (int e = 0; e < 8; e += 2) {
          a0 += bf2f(qv[c][e]) * bf2f(u[e]);
          a1 += bf2f(qv[c][e + 1]) * bf2f(u[e + 1]);
        }
      }
      sls[hh][i][j] = (a0 + a1) * 0.125f;
    }
    float mx = -1e30f;
#pragma unroll 1
    for (int j = 0; j < SEGL; j++) mx = fmaxf(mx, sls[hh][i][j]);
    float sum = 0.0f;
#pragma unroll 1
    for (int j = 0; j < SEGL; j++) { float e = __expf(sls[hh][i][j] - mx); sls[hh][i][j] = e; sum += e; }
    inv = 1.0f / sum;
  }
  __syncthreads();
  if (active) {
#pragma unroll
    for (int d0 = 0; d0 < DH; d0 += 8) {
      float acc[8] = {};
#pragma unroll 1
      for (int j = 0; j < SEGL; j++) {
        const float pj = sls[hh][i][j];
        ushort8 u = *reinterpret_cast<const ushort8*>(&vls[j][hh * DH + d0]);
#pragma unroll
        for (int e = 0; e < 8; e++) acc[e] += pj * bf2f(u[e]);
      }
      unsigned short pk[8];
#pragma unroll
      for (int e = 0; e < 8; e++) pk[e] = f2bf(acc[e] * inv);
      const int colr = hh * DH + ((d0 + i * 8) & (DH - 1));
      *reinterpret_cast<uint4*>(&kls[i][colr]) = *reinterpret_cast<uint4*>(pk);
    }
  }
  __syncthreads();
#pragma unroll
  for (int it = 0; it < 3; it++) {
    const int c = it * 256 + tid;
    if (c < SEGL * 32) {
      const int j = c >> 5, off = (c & 31) * 8;
      const int hl = off >> 6, d = off & (DH - 1);
      const int colr = hl * DH + ((d + j * 8) & (DH - 1));
      *reinterpret_cast<uint4*>(qkv + (row0 + (size_t)j * B_BATCH) * QKVW + colbase + off) =
          *reinterpret_cast<const uint4*>(&kls[j][colr]);
    }
  }
}

// ---------- final: pooled = mean_b h ; out = pooled @ fc_w + fc_b ----------
__global__ __launch_bounds__(256)
void pool_fc(const __hip_bfloat16* __restrict__ h, const float* __restrict__ fcw,
             const float* __restrict__ fcb, float* __restrict__ out) {
  const int t = blockIdx.x, tid = threadIdx.x;
  float a[4] = {0, 0, 0, 0};
#pragma unroll
  for (int b = 0; b < B_BATCH; b++) {
    float v[4];
    unpack4(*reinterpret_cast<const uint2*>(h + ((size_t)t * B_BATCH + b) * D_MODEL + tid * 4), v);
#pragma unroll
    for (int e = 0; e < 4; e++) a[e] += v[e];
  }
  const int d0 = tid * 4;
  float pacc[5];
#pragma unroll
  for (int c = 0; c < 5; c++)
    pacc[c] = (a[0] * fcw[(d0 + 0) * 5 + c] + a[1] * fcw[(d0 + 1) * 5 + c] +
               a[2] * fcw[(d0 + 2) * 5 + c] + a[3] * fcw[(d0 + 3) * 5 + c]) * (1.0f / B_BATCH);
#pragma unroll
  for (int off = 32; off >= 1; off >>= 1)
#pragma unroll
    for (int c = 0; c < 5; c++) pacc[c] += __shfl_xor(pacc[c], off);
  __shared__ float red[4][5];
  if ((tid & 63) == 0) {
#pragma unroll
    for (int c = 0; c < 5; c++) red[tid >> 6][c] = pacc[c];
  }
  __syncthreads();
  if (tid < 5)
    out[(size_t)t * 5 + tid] = red[0][tid] + red[1][tid] + red[2][tid] + red[3][tid] + fcb[tid];
}

// ---------- launch ----------
extern "C" void kernel_launch(void* const* d_in, const int* in_sizes, int n_in,
                              void* d_out, int out_size, void* d_ws, size_t ws_size,
                              hipStream_t stream) {
  const float* x    = (const float*)d_in[0];
  const float* lnp  = (const float*)d_in[2];
  const float* Wq   = (const float*)d_in[3];
  const float* bq   = (const float*)d_in[4];
  const float* Wkv  = (const float*)d_in[5];
  const float* bkv  = (const float*)d_in[6];
  const float* Wout = (const float*)d_in[7];
  const float* bout = (const float*)d_in[8];
  const float* W1   = (const float*)d_in[9];
  const float* b1   = (const float*)d_in[10];
  const float* W2   = (const float*)d_in[11];
  const float* b2   = (const float*)d_in[12];
  const float* fcw  = (const float*)d_in[13];
  const float* fcb  = (const float*)d_in[14];

  char* p = (char*)d_ws;
  size_t off = 0;
  auto take = [&](size_t bytes) -> char* { char* q = p + off; off += (bytes + 255) & ~(size_t)255; return q; };

  __hip_bfloat16* h    = (__hip_bfloat16*)take((size_t)M_ROWS * D_MODEL * 2);
  __hip_bfloat16* hn   = (__hip_bfloat16*)take((size_t)M_ROWS * D_MODEL * 2);
  __hip_bfloat16* qkvb = (__hip_bfloat16*)take((size_t)M_ROWS * QKVW * 2);
  __hip_bfloat16* f1   = qkvb + D_MODEL;   // strided [M][1024] at ldc=QKVW (k slice, dead post-attn)

  const size_t WL  = (size_t)D_MODEL * D_MODEL;
  const size_t WQKV = 3 * WL;
  const size_t fullBytes = (L_LAYERS * (WQKV + 3 * WL)) * 2;
  const bool full = ws_size >= off + fullBytes + (size_t)(16 << 20);

  __hip_bfloat16 *WqkvT, *WoutT, *W1T, *W2T;
  if (full) {
    WqkvT = (__hip_bfloat16*)take(L_LAYERS * WQKV * 2);
    WoutT = (__hip_bfloat16*)take(L_LAYERS * WL * 2);
    W1T   = (__hip_bfloat16*)take(L_LAYERS * WL * 2);
    W2T   = (__hip_bfloat16*)take(L_LAYERS * WL * 2);
    trans_w<<<dim3(32, 32, L_LAYERS), 256, 0, stream>>>(Wq,  WqkvT,      D_MODEL, D_MODEL,     WQKV);
    trans_w<<<dim3(64, 32, L_LAYERS), 256, 0, stream>>>(Wkv, WqkvT + WL, D_MODEL, 2 * D_MODEL, WQKV);
    trans_w<<<dim3(32, 32, L_LAYERS), 256, 0, stream>>>(Wout, WoutT, D_MODEL, D_MODEL, WL);
    trans_w<<<dim3(32, 32, L_LAYERS), 256, 0, stream>>>(W1,   W1T,   D_MODEL, D_MODEL, WL);
    trans_w<<<dim3(32, 32, L_LAYERS), 256, 0, stream>>>(W2,   W2T,   D_MODEL, D_MODEL, WL);
  } else {
    WqkvT = (__hip_bfloat16*)take(WQKV * 2);
    WoutT = (__hip_bfloat16*)take(WL * 2);
    W1T   = (__hip_bfloat16*)take(WL * 2);
    W2T   = (__hip_bfloat16*)take(WL * 2);
  }

  const float* g00 = lnp;
  const float* b00 = lnp + D_MODEL;
  xpose_ln<<<M_ROWS, 256, 0, stream>>>(x, h, hn, g00, b00);

  const int BSEL_OFF = 1 << 30;
  for (int l = 0; l < L_LAYERS; l++) {
    const size_t lw = (size_t)l * WL;
    const __hip_bfloat16* wqkv = full ? WqkvT + l * WQKV : WqkvT;
    const __hip_bfloat16* wout = full ? WoutT + lw : WoutT;
    const __hip_bfloat16* w1   = full ? W1T   + lw : W1T;
    const __hip_bfloat16* w2   = full ? W2T   + lw : W2T;
    if (!full) {
      trans_w<<<dim3(32, 32, 1), 256, 0, stream>>>(Wq + lw,      WqkvT,      D_MODEL, D_MODEL,     0);
      trans_w<<<dim3(64, 32, 1), 256, 0, stream>>>(Wkv + 2 * lw, WqkvT + WL, D_MODEL, 2 * D_MODEL, 0);
      trans_w<<<dim3(32, 32, 1), 256, 0, stream>>>(Wout + lw, WoutT, D_MODEL, D_MODEL, 0);
      trans_w<<<dim3(32, 32, 1), 256, 0, stream>>>(W1 + lw,   W1T,   D_MODEL, D_MODEL, 0);
      trans_w<<<dim3(32, 32, 1), 256, 0, stream>>>(W2 + lw,   W2T,   D_MODEL, D_MODEL, 0);
    }
    const float* g2 = lnp + ((size_t)l * 6 + 2) * D_MODEL;
    const float* g3 = lnp + ((size_t)l * 6 + 3) * D_MODEL;
    const float* g4 = lnp + ((size_t)l * 6 + 4) * D_MODEL;
    const float* g5 = lnp + ((size_t)l * 6 + 5) * D_MODEL;

    // fused qkv projection: C = [q|k|v], N=3072
    gemm_bt<EPI_BF16><<<dim3(12 * 125), 512, 0, stream>>>(
        hn, wqkv, bq + (size_t)l * D_MODEL, bkv + (size_t)l * 2 * D_MODEL, D_MODEL,
        nullptr, qkvb, QKVW, D_MODEL, D_MODEL, QKVW);
    attn_k<<<NSEG * B_BATCH * HGN, 256, 0, stream>>>(qkvb);
    gemm_bt<EPI_RES><<<dim3(4 * 125), 512, 0, stream>>>(
        qkvb, wout, bout + (size_t)l * D_MODEL, bout + (size_t)l * D_MODEL, BSEL_OFF,
        h, h, D_MODEL, D_MODEL, QKVW, D_MODEL);
    ln_k<<<M_ROWS, 256, 0, stream>>>(h, hn, g2, g3);
    gemm_bt<EPI_RELU><<<dim3(4 * 125), 512, 0, stream>>>(
        hn, w1, b1 + (size_t)l * D_MODEL, b1 + (size_t)l * D_MODEL, BSEL_OFF,
        nullptr, f1, D_MODEL, D_MODEL, D_MODEL, QKVW);
    gemm_bt<EPI_RES><<<dim3(4 * 125), 512, 0, stream>>>(
        f1, w2, b2 + (size_t)l * D_MODEL, b2 + (size_t)l * D_MODEL, BSEL_OFF,
        h, h, D_MODEL, D_MODEL, QKVW, D_MODEL);
    if (l + 1 < L_LAYERS) {
      const float* g0n = lnp + ((size_t)(l + 1) * 6 + 0) * D_MODEL;
      const float* b0n = lnp + ((size_t)(l + 1) * 6 + 1) * D_MODEL;
      dual_ln<<<M_ROWS, 256, 0, stream>>>(h, h, hn, g4, g5, g0n, b0n);
    } else {
      ln_k<<<M_ROWS, 256, 0, stream>>>(h, h, g4, g5);
    }
  }

  pool_fc<<<T_TIME, 256, 0, stream>>>(h, fcw, fcb, (float*)d_out);
}